// Round 1
// baseline (497.323 us; speedup 1.0000x reference)
//
#include <hip/hip_runtime.h>
#include <stdint.h>

#define SS 256
#define FAR_F 100.0f

struct __align__(16) FaceCoef {
    float4 c0;  // a0, b0, c0, a1
    float4 c1;  // b1, c1, inv_area (NaN if degenerate), pad
    float4 c2;  // 1/z0, 1/z1, 1/z2, pad
};

// ---------------- prep: per (b,f) edge coefficients + bbox ----------------
__global__ void nmr_prep(const float* __restrict__ verts,
                         const int* __restrict__ faces,
                         FaceCoef* __restrict__ fc,
                         uint32_t* __restrict__ bbx,
                         int B, int N, int F)
{
#pragma clang fp contract(off)
    int idx = blockIdx.x * blockDim.x + threadIdx.x;
    if (idx >= B * F) return;
    int b = idx / F;
    int f = idx - b * F;

    int i0 = faces[3 * f + 0], i1 = faces[3 * f + 1], i2 = faces[3 * f + 2];
    const float* vb = verts + (size_t)(3 * N) * b;
    const float EZ = -1.7320508075688772f;  // f32(EYE_Z)

    // v = verts * [1,-1,1] - [0,0,EYE_Z]  (exact: negate + IEEE sub)
    float x0 = vb[3 * i0 + 0], y0 = -vb[3 * i0 + 1], z0 = vb[3 * i0 + 2] - EZ;
    float x1 = vb[3 * i1 + 0], y1 = -vb[3 * i1 + 1], z1 = vb[3 * i1 + 2] - EZ;
    float x2 = vb[3 * i2 + 0], y2 = -vb[3 * i2 + 1], z2 = vb[3 * i2 + 2] - EZ;

    // exactly numpy's op order, contraction off
    float area = (x1 - x0) * (y2 - y0) - (x2 - x0) * (y1 - y0);
    bool ok = fabsf(area) > 1e-7f;
    float ia = ok ? (1.0f / area) : __int_as_float(0x7fc00000);  // NaN kills all compares

    FaceCoef c;
    c.c0 = make_float4(x1 * y2 - x2 * y1, y1 - y2, x2 - x1, x2 * y0 - x0 * y2);
    c.c1 = make_float4(y2 - y0, x0 - x2, ia, 0.0f);
    c.c2 = make_float4(1.0f / z0, 1.0f / z1, 1.0f / z2, 0.0f);
    fc[idx] = c;

    // conservative pixel bbox (padded ±1 px for float slop); empty if degenerate
    uint32_t bb = 255u | (0u << 8) | (255u << 16) | (0u << 24);  // jlo>jhi: never matches
    if (ok) {
        float xmn = fminf(x0, fminf(x1, x2)), xmx = fmaxf(x0, fmaxf(x1, x2));
        float ymn = fminf(y0, fminf(y1, y2)), ymx = fmaxf(y0, fmaxf(y1, y2));
        // px_j = (2j+1-256)/256  >= xmn  <=>  j >= 128*(xmn+1) - 0.5
        int jlo = (int)floorf(128.0f * (xmn + 1.0f) - 0.5f) - 1;
        int jhi = (int)ceilf (128.0f * (xmx + 1.0f) - 0.5f) + 1;
        // py_i = (255-2i)/256 (decreasing in i)
        int ilo = (int)floorf((255.0f - 256.0f * ymx) * 0.5f) - 1;
        int ihi = (int)ceilf ((255.0f - 256.0f * ymn) * 0.5f) + 1;
        jlo = max(0, min(255, jlo)); jhi = max(0, min(255, jhi));
        ilo = max(0, min(255, ilo)); ihi = max(0, min(255, ihi));
        if (jhi >= jlo && ihi >= ilo)
            bb = (uint32_t)jlo | ((uint32_t)jhi << 8) | ((uint32_t)ilo << 16) | ((uint32_t)ihi << 24);
    }
    bbx[idx] = bb;
}

// ---------------- raster: one block per (batch, 16x16 tile) ----------------
__global__ __launch_bounds__(256) void nmr_raster(
    const FaceCoef* __restrict__ fc,
    const uint32_t* __restrict__ bbx,
    float* __restrict__ out,
    int B, int F)
{
#pragma clang fp contract(off)
    extern __shared__ uint16_t list[];   // F entries
    __shared__ int cnt;

    const int tid = threadIdx.x;
    const int bid = blockIdx.x;
    const int b    = bid >> 8;
    const int tile = bid & 255;
    const int tj0 = (tile & 15) << 4;
    const int ti0 = (tile >> 4) << 4;

    if (tid == 0) cnt = 0;
    __syncthreads();

    // phase 1: compact faces whose bbox overlaps this tile
    const uint32_t* bb = bbx + (size_t)b * F;
    for (int f = tid; f < F; f += 256) {
        uint32_t v = bb[f];
        int jlo = v & 255, jhi = (v >> 8) & 255, ilo = (v >> 16) & 255, ihi = (int)(v >> 24);
        if (jlo <= tj0 + 15 && jhi >= tj0 && ilo <= ti0 + 15 && ihi >= ti0) {
            int p = atomicAdd(&cnt, 1);
            list[p] = (uint16_t)f;
        }
    }
    __syncthreads();

    const int n = cnt;
    const int j = tj0 + (tid & 15);
    const int i = ti0 + (tid >> 4);
    const float px = (float)(2 * j + 1 - SS) * (1.0f / (float)SS);   // exact
    const float py = (float)(SS - 1 - 2 * i) * (1.0f / (float)SS);   // exact

    const FaceCoef* fb = fc + (size_t)b * F;
    float best = 0.0f;  // max of zinv over covering faces

    for (int k = 0; k < n; ++k) {
        int f = __builtin_amdgcn_readfirstlane((int)list[k]);  // uniform -> scalar loads
        float4 A  = fb[f].c0;
        float4 Bv = fb[f].c1;
        float4 Cv = fb[f].c2;
        // bit-exact numpy op order (no FMA): e = (a + b*px) + c*py; w = e*ia
        float e0 = (A.x + A.y * px) + A.z * py;
        float w0 = e0 * Bv.z;
        float e1 = (A.w + Bv.x * px) + Bv.y * py;
        float w1 = e1 * Bv.z;
        float w2 = (1.0f - w0) - w1;
        float zi = (w0 * Cv.x + w1 * Cv.y) + w2 * Cv.z;  // ~1ulp-off zinv: far from cull bounds
        bool ins = (w0 >= 0.0f) && (w1 >= 0.0f) && (w2 >= 0.0f) &&
                   (zi > 0.01f) && (zi < 10.0f);          // == (zq>NEAR && zq<FAR)
        if (ins) best = fmaxf(best, zi);
    }

    const size_t pix = (size_t)b * (SS * SS) + (size_t)i * SS + j;
    float zb = FAR_F, sil = 0.0f;
    if (best > 0.0f) { zb = 1.0f / best; sil = 1.0f; }   // correctly-rounded: == min(1/zinv_k)
    out[pix] = sil;
    out[(size_t)B * (SS * SS) + pix] = zb;
}

// ---------------- host ----------------
extern "C" void kernel_launch(void* const* d_in, const int* in_sizes, int n_in,
                              void* d_out, int out_size, void* d_ws, size_t ws_size,
                              hipStream_t stream)
{
    const float* verts = (const float*)d_in[0];
    const int*   faces = (const int*)d_in[1];
    float* out = (float*)d_out;

    const int B = out_size / (2 * SS * SS);          // 16
    const int F = in_sizes[1] / 3;                   // 1538
    const int N = in_sizes[0] / (3 * B);             // 778

    FaceCoef* fc  = (FaceCoef*)d_ws;
    uint32_t* bbx = (uint32_t*)((char*)d_ws + (size_t)B * F * sizeof(FaceCoef));

    const int total = B * F;
    nmr_prep<<<(total + 255) / 256, 256, 0, stream>>>(verts, faces, fc, bbx, B, N, F);

    const size_t smem = (size_t)F * sizeof(uint16_t);
    nmr_raster<<<B * 256, 256, smem, stream>>>(fc, bbx, out, B, F);
}

// Round 2
// 449.733 us; speedup vs baseline: 1.1058x; 1.1058x over previous
//
#include <hip/hip_runtime.h>
#include <stdint.h>

#define SS 256
#define FAR_F 100.0f
#define CAP 768          // faces staged in LDS per tile
#define OVMAX 1024       // overflow index capacity (F - CAP <= 770 for F=1538)

struct __align__(16) FaceCoef {
    float4 c0;  // a0, b0, c0, a1
    float4 c1;  // b1, c1, inv_area (NaN if degenerate), pad
    float4 c2;  // 1/z0, 1/z1, 1/z2, pad
};

// ---------------- prep: per (b,f) edge coefficients + bbox ----------------
__global__ void nmr_prep(const float* __restrict__ verts,
                         const int* __restrict__ faces,
                         FaceCoef* __restrict__ fc,
                         uint32_t* __restrict__ bbx,
                         int B, int N, int F)
{
#pragma clang fp contract(off)
    int idx = blockIdx.x * blockDim.x + threadIdx.x;
    if (idx >= B * F) return;
    int b = idx / F;
    int f = idx - b * F;

    int i0 = faces[3 * f + 0], i1 = faces[3 * f + 1], i2 = faces[3 * f + 2];
    const float* vb = verts + (size_t)(3 * N) * b;
    const float EZ = -1.7320508075688772f;  // f32(EYE_Z)

    float x0 = vb[3 * i0 + 0], y0 = -vb[3 * i0 + 1], z0 = vb[3 * i0 + 2] - EZ;
    float x1 = vb[3 * i1 + 0], y1 = -vb[3 * i1 + 1], z1 = vb[3 * i1 + 2] - EZ;
    float x2 = vb[3 * i2 + 0], y2 = -vb[3 * i2 + 1], z2 = vb[3 * i2 + 2] - EZ;

    // exactly numpy's op order, contraction off
    float area = (x1 - x0) * (y2 - y0) - (x2 - x0) * (y1 - y0);
    bool ok = fabsf(area) > 1e-7f;
    float ia = ok ? (1.0f / area) : __int_as_float(0x7fc00000);  // NaN kills all compares

    FaceCoef c;
    c.c0 = make_float4(x1 * y2 - x2 * y1, y1 - y2, x2 - x1, x2 * y0 - x0 * y2);
    c.c1 = make_float4(y2 - y0, x0 - x2, ia, 0.0f);
    c.c2 = make_float4(1.0f / z0, 1.0f / z1, 1.0f / z2, 0.0f);
    fc[idx] = c;

    // conservative pixel bbox (padded ±1 px); empty if degenerate
    uint32_t bb = 255u | (0u << 8) | (255u << 16) | (0u << 24);
    if (ok) {
        float xmn = fminf(x0, fminf(x1, x2)), xmx = fmaxf(x0, fmaxf(x1, x2));
        float ymn = fminf(y0, fminf(y1, y2)), ymx = fmaxf(y0, fmaxf(y1, y2));
        int jlo = (int)floorf(128.0f * (xmn + 1.0f) - 0.5f) - 1;
        int jhi = (int)ceilf (128.0f * (xmx + 1.0f) - 0.5f) + 1;
        int ilo = (int)floorf((255.0f - 256.0f * ymx) * 0.5f) - 1;
        int ihi = (int)ceilf ((255.0f - 256.0f * ymn) * 0.5f) + 1;
        jlo = max(0, min(255, jlo)); jhi = max(0, min(255, jhi));
        ilo = max(0, min(255, ilo)); ihi = max(0, min(255, ihi));
        if (jhi >= jlo && ihi >= ilo)
            bb = (uint32_t)jlo | ((uint32_t)jhi << 8) | ((uint32_t)ilo << 16) | ((uint32_t)ihi << 24);
    }
    bbx[idx] = bb;
}

// ---------------- raster: one block per (batch, 16x16 tile) ----------------
__global__ __launch_bounds__(256) void nmr_raster(
    const FaceCoef* __restrict__ fc,
    const uint32_t* __restrict__ bbx,
    float* __restrict__ out,
    int B, int F)
{
#pragma clang fp contract(off)
    __shared__ float4  scoef[3 * CAP];    // 36 KB: staged coefficients
    __shared__ uint16_t ovlist[OVMAX];    // 2 KB: overflow face indices
    __shared__ int cnt;

    const int tid = threadIdx.x;
    const int bid = blockIdx.x;
    const int b    = bid >> 8;
    const int tile = bid & 255;
    const int tj0 = (tile & 15) << 4;
    const int ti0 = (tile >> 4) << 4;

    if (tid == 0) cnt = 0;
    __syncthreads();

    // phase 1: compact overlapping faces; stage coefs of first CAP into LDS
    const uint32_t* bb = bbx + (size_t)b * F;
    const FaceCoef* fb = fc + (size_t)b * F;
    for (int f = tid; f < F; f += 256) {
        uint32_t v = bb[f];
        int jlo = v & 255, jhi = (v >> 8) & 255, ilo = (v >> 16) & 255, ihi = (int)(v >> 24);
        if (jlo <= tj0 + 15 && jhi >= tj0 && ilo <= ti0 + 15 && ihi >= ti0) {
            int p = atomicAdd(&cnt, 1);
            if (p < CAP) {
                scoef[3 * p + 0] = fb[f].c0;
                scoef[3 * p + 1] = fb[f].c1;
                scoef[3 * p + 2] = fb[f].c2;
            } else if (p - CAP < OVMAX) {
                ovlist[p - CAP] = (uint16_t)f;
            }
        }
    }
    __syncthreads();

    const int n = cnt;
    const int j = tj0 + (tid & 15);
    const int i = ti0 + (tid >> 4);
    const float px = (float)(2 * j + 1 - SS) * (1.0f / (float)SS);   // exact
    const float py = (float)(SS - 1 - 2 * i) * (1.0f / (float)SS);   // exact

    float best = 0.0f;  // max of zinv over covering faces

    // phase 2a: LDS-staged faces (uniform-address ds_read -> broadcast, pipelined)
    const int nl = min(n, CAP);
#pragma unroll 4
    for (int k = 0; k < nl; ++k) {
        float4 A  = scoef[3 * k + 0];
        float4 Bv = scoef[3 * k + 1];
        float4 Cv = scoef[3 * k + 2];
        float e0 = (A.x + A.y * px) + A.z * py;      // bit-exact numpy op order
        float w0 = e0 * Bv.z;
        float e1 = (A.w + Bv.x * px) + Bv.y * py;
        float w1 = e1 * Bv.z;
        float w2 = (1.0f - w0) - w1;
        float zi = (w0 * Cv.x + w1 * Cv.y) + w2 * Cv.z;
        bool ins = (w0 >= 0.0f) && (w1 >= 0.0f) && (w2 >= 0.0f) &&
                   (zi > 0.01f) && (zi < 10.0f);
        best = ins ? fmaxf(best, zi) : best;
    }

    // phase 2b: rare overflow beyond CAP (scalar-load path)
    for (int k = CAP; k < n; ++k) {
        int f = __builtin_amdgcn_readfirstlane((int)ovlist[k - CAP]);
        float4 A  = fb[f].c0;
        float4 Bv = fb[f].c1;
        float4 Cv = fb[f].c2;
        float e0 = (A.x + A.y * px) + A.z * py;
        float w0 = e0 * Bv.z;
        float e1 = (A.w + Bv.x * px) + Bv.y * py;
        float w1 = e1 * Bv.z;
        float w2 = (1.0f - w0) - w1;
        float zi = (w0 * Cv.x + w1 * Cv.y) + w2 * Cv.z;
        bool ins = (w0 >= 0.0f) && (w1 >= 0.0f) && (w2 >= 0.0f) &&
                   (zi > 0.01f) && (zi < 10.0f);
        best = ins ? fmaxf(best, zi) : best;
    }

    const size_t pix = (size_t)b * (SS * SS) + (size_t)i * SS + j;
    float zb = FAR_F, sil = 0.0f;
    if (best > 0.0f) { zb = 1.0f / best; sil = 1.0f; }   // == min(1/zinv_k)
    out[pix] = sil;
    out[(size_t)B * (SS * SS) + pix] = zb;
}

// ---------------- host ----------------
extern "C" void kernel_launch(void* const* d_in, const int* in_sizes, int n_in,
                              void* d_out, int out_size, void* d_ws, size_t ws_size,
                              hipStream_t stream)
{
    const float* verts = (const float*)d_in[0];
    const int*   faces = (const int*)d_in[1];
    float* out = (float*)d_out;

    const int B = out_size / (2 * SS * SS);          // 16
    const int F = in_sizes[1] / 3;                   // 1538
    const int N = in_sizes[0] / (3 * B);             // 778

    FaceCoef* fc  = (FaceCoef*)d_ws;
    uint32_t* bbx = (uint32_t*)((char*)d_ws + (size_t)B * F * sizeof(FaceCoef));

    const int total = B * F;
    nmr_prep<<<(total + 255) / 256, 256, 0, stream>>>(verts, faces, fc, bbx, B, N, F);

    nmr_raster<<<B * 256, 256, 0, stream>>>(fc, bbx, out, B, F);
}

// Round 3
// 216.942 us; speedup vs baseline: 2.2924x; 2.0731x over previous
//
#include <hip/hip_runtime.h>
#include <hip/hip_fp16.h>
#include <stdint.h>

#define SS 256
#define FAR_F 100.0f
#define CAPB 272           // max faces per staged chunk
#define REG 32             // region size in px
#define NREG 64            // regions per batch (8x8)

struct __align__(16) PackedCoef {
    float4 q0;  // A0,B0,C0,A1  (edge coefs premultiplied by inv_area)
    float4 q1;  // B1,C1, bits(d0h|d1h<<16), bits(rz2h|faceid<<16)
};

static __device__ __forceinline__ unsigned short f2h(float x) {
    return __half_as_ushort(__float2half(x));
}

// ---------------- prep: per (b,f) packed coefficients + bbox ----------------
__global__ void nmr_prep(const float* __restrict__ verts,
                         const int* __restrict__ faces,
                         PackedCoef* __restrict__ pc,
                         uint32_t* __restrict__ bbx,
                         int B, int N, int F)
{
#pragma clang fp contract(off)
    int idx = blockIdx.x * blockDim.x + threadIdx.x;
    if (idx >= B * F) return;
    int b = idx / F;
    int f = idx - b * F;

    int i0 = faces[3 * f + 0], i1 = faces[3 * f + 1], i2 = faces[3 * f + 2];
    const float* vb = verts + (size_t)(3 * N) * b;
    const float EZ = -1.7320508075688772f;  // f32(EYE_Z)

    float x0 = vb[3 * i0 + 0], y0 = -vb[3 * i0 + 1], z0 = vb[3 * i0 + 2] - EZ;
    float x1 = vb[3 * i1 + 0], y1 = -vb[3 * i1 + 1], z1 = vb[3 * i1 + 2] - EZ;
    float x2 = vb[3 * i2 + 0], y2 = -vb[3 * i2 + 1], z2 = vb[3 * i2 + 2] - EZ;

    float area = (x1 - x0) * (y2 - y0) - (x2 - x0) * (y1 - y0);
    bool ok = fabsf(area) > 1e-7f;
    float ia = ok ? (1.0f / area) : 0.0f;

    // edge coefs (numpy order), then premultiply by ia (each op rounded; covered by eps band)
    float a0 = x1 * y2 - x2 * y1, b0 = y1 - y2, c0 = x2 - x1;
    float a1 = x2 * y0 - x0 * y2, b1 = y2 - y0, c1 = x0 - x2;
    float rz0 = 1.0f / z0, rz1 = 1.0f / z1, rz2 = 1.0f / z2;
    float d0 = rz0 - rz2, d1 = rz1 - rz2;

    PackedCoef c;
    c.q0 = make_float4(a0 * ia, b0 * ia, c0 * ia, a1 * ia);
    uint32_t dd = (uint32_t)f2h(d0) | ((uint32_t)f2h(d1) << 16);
    uint32_t rr = (uint32_t)f2h(rz2) | ((uint32_t)f << 16);
    c.q1 = make_float4(b1 * ia, c1 * ia, __uint_as_float(dd), __uint_as_float(rr));
    pc[idx] = c;

    // conservative pixel bbox (padded +-1 px); empty if degenerate
    uint32_t bb = 255u | (0u << 8) | (255u << 16) | (0u << 24);
    if (ok) {
        float xmn = fminf(x0, fminf(x1, x2)), xmx = fmaxf(x0, fmaxf(x1, x2));
        float ymn = fminf(y0, fminf(y1, y2)), ymx = fmaxf(y0, fmaxf(y1, y2));
        int jlo = (int)floorf(128.0f * (xmn + 1.0f) - 0.5f) - 1;
        int jhi = (int)ceilf (128.0f * (xmx + 1.0f) - 0.5f) + 1;
        int ilo = (int)floorf((255.0f - 256.0f * ymx) * 0.5f) - 1;
        int ihi = (int)ceilf ((255.0f - 256.0f * ymn) * 0.5f) + 1;
        jlo = max(0, min(255, jlo)); jhi = max(0, min(255, jhi));
        ilo = max(0, min(255, ilo)); ihi = max(0, min(255, ihi));
        if (jhi >= jlo && ihi >= ilo)
            bb = (uint32_t)jlo | ((uint32_t)jhi << 8) | ((uint32_t)ilo << 16) | ((uint32_t)ihi << 24);
    }
    bbx[idx] = bb;
}

// ---------------- raster: block = (batch, 32x32 region, face-chunk) ----------------
__global__ __launch_bounds__(256, 6) void nmr_raster(
    const PackedCoef* __restrict__ pc,
    const uint32_t* __restrict__ bbx,
    const float* __restrict__ verts,
    const int* __restrict__ faces,
    uint32_t* __restrict__ zu,
    int B, int N, int F, int NCHn, int CH)
{
#pragma clang fp contract(off)
    __shared__ float4 sq[2 * CAPB];
    __shared__ int cnt;

    int bid = blockIdx.x;
    int ch = bid % NCHn; int t = bid / NCHn;
    int reg = t % NREG;  int b = t / NREG;
    const int rj0 = (reg & 7) * REG;
    const int ri0 = (reg >> 3) * REG;

    if (threadIdx.x == 0) cnt = 0;
    __syncthreads();

    // phase 1: stage packed coefs of overlapping faces in [f0,f1)
    const int f0 = ch * CH, f1 = min(F, f0 + CH);
    const uint32_t* bb = bbx + (size_t)b * F;
    const PackedCoef* pb = pc + (size_t)b * F;
    for (int f = f0 + (int)threadIdx.x; f < f1; f += 256) {
        uint32_t v = bb[f];
        int jlo = v & 255, jhi = (v >> 8) & 255, ilo = (v >> 16) & 255, ihi = (int)(v >> 24);
        if (jlo <= rj0 + REG - 1 && jhi >= rj0 && ilo <= ri0 + REG - 1 && ihi >= ri0) {
            int p = atomicAdd(&cnt, 1);
            sq[2 * p + 0] = pb[f].q0;
            sq[2 * p + 1] = pb[f].q1;
        }
    }
    __syncthreads();

    const int n = cnt;
    const int lane = threadIdx.x & 63, w = threadIdx.x >> 6;
    const int j = rj0 + ((w & 1) << 4) + (lane & 15);
    const int irow0 = ri0 + ((w >> 1) << 4) + (lane >> 4);   // rows irow0 + 4r
    const float px = (float)(2 * j + 1 - SS) * (1.0f / SS);
    const float py0 = (float)(SS - 1 - 2 * (irow0 + 0))  * (1.0f / SS);
    const float py1 = (float)(SS - 1 - 2 * (irow0 + 4))  * (1.0f / SS);
    const float py2 = (float)(SS - 1 - 2 * (irow0 + 8))  * (1.0f / SS);
    const float py3 = (float)(SS - 1 - 2 * (irow0 + 12)) * (1.0f / SS);

    float best0 = 0.0f, best1 = 0.0f, best2 = 0.0f, best3 = 0.0f;

    for (int k = 0; k < n; ++k) {
        float4 q0 = sq[2 * k + 0];
        float4 q1 = sq[2 * k + 1];
        const float A0 = q0.x, B0 = q0.y, C0 = q0.z, A1 = q0.w;
        const float B1 = q1.x, C1 = q1.y;
        uint32_t dd = __float_as_uint(q1.z);
        uint32_t rr = __float_as_uint(q1.w);
        float d0  = __half2float(__ushort_as_half((unsigned short)(dd & 0xffffu)));
        float d1  = __half2float(__ushort_as_half((unsigned short)(dd >> 16)));
        float rz2 = __half2float(__ushort_as_half((unsigned short)(rr & 0xffffu)));

        float mag = fmaxf(fmaxf(fabsf(A0), fabsf(B0)), fmaxf(fabsf(C0), fabsf(A1)));
        mag = fmaxf(mag, fmaxf(fabsf(B1), fmaxf(fabsf(C1), 1.0f)));
        const float epsf = 3e-6f * mag;

        const float w0b = __builtin_fmaf(B0, px, A0);
        const float w1b = __builtin_fmaf(B1, px, A1);

        float w0_0 = __builtin_fmaf(C0, py0, w0b), w1_0 = __builtin_fmaf(C1, py0, w1b);
        float w0_1 = __builtin_fmaf(C0, py1, w0b), w1_1 = __builtin_fmaf(C1, py1, w1b);
        float w0_2 = __builtin_fmaf(C0, py2, w0b), w1_2 = __builtin_fmaf(C1, py2, w1b);
        float w0_3 = __builtin_fmaf(C0, py3, w0b), w1_3 = __builtin_fmaf(C1, py3, w1b);
        float w2_0 = (1.0f - w0_0) - w1_0, w2_1 = (1.0f - w0_1) - w1_1;
        float w2_2 = (1.0f - w0_2) - w1_2, w2_3 = (1.0f - w0_3) - w1_3;
        float m0 = fminf(w0_0, fminf(w1_0, w2_0)), m1 = fminf(w0_1, fminf(w1_1, w2_1));
        float m2 = fminf(w0_2, fminf(w1_2, w2_2)), m3 = fminf(w0_3, fminf(w1_3, w2_3));
        float zi0 = __builtin_fmaf(w1_0, d1, __builtin_fmaf(w0_0, d0, rz2));
        float zi1 = __builtin_fmaf(w1_1, d1, __builtin_fmaf(w0_1, d0, rz2));
        float zi2 = __builtin_fmaf(w1_2, d1, __builtin_fmaf(w0_2, d0, rz2));
        float zi3 = __builtin_fmaf(w1_3, d1, __builtin_fmaf(w0_3, d0, rz2));
        float e0 = __builtin_fmaf(fmaxf(fabsf(w0_0), fabsf(w1_0)), 6e-7f, epsf);
        float e1 = __builtin_fmaf(fmaxf(fabsf(w0_1), fabsf(w1_1)), 6e-7f, epsf);
        float e2 = __builtin_fmaf(fmaxf(fabsf(w0_2), fabsf(w1_2)), 6e-7f, epsf);
        float e3 = __builtin_fmaf(fmaxf(fabsf(w0_3), fabsf(w1_3)), 6e-7f, epsf);
        bool amb = (fabsf(m0) <= e0) | (fabsf(m1) <= e1) | (fabsf(m2) <= e2) | (fabsf(m3) <= e3);
        bool ins0 = m0 >= 0.0f, ins1 = m1 >= 0.0f, ins2 = m2 >= 0.0f, ins3 = m3 >= 0.0f;

        if (__any(amb)) {
            // exact numpy-order recompute for the whole wave (rare)
            int fid = __builtin_amdgcn_readfirstlane((int)(rr >> 16));
            int i0f = faces[3 * fid + 0], i1f = faces[3 * fid + 1], i2f = faces[3 * fid + 2];
            const float* vb = verts + (size_t)(3 * N) * b;
            float x0 = vb[3 * i0f + 0], y0 = -vb[3 * i0f + 1];
            float x1 = vb[3 * i1f + 0], y1 = -vb[3 * i1f + 1];
            float x2 = vb[3 * i2f + 0], y2 = -vb[3 * i2f + 1];
            float area = (x1 - x0) * (y2 - y0) - (x2 - x0) * (y1 - y0);
            float ia = 1.0f / area;  // staged faces are non-degenerate
            float a0 = x1 * y2 - x2 * y1, b0e = y1 - y2, c0e = x2 - x1;
            float a1 = x2 * y0 - x0 * y2, b1e = y2 - y0, c1e = x0 - x2;
            float e0b = a0 + b0e * px;
            float e1b = a1 + b1e * px;
            {
                float u0 = (e0b + c0e * py0) * ia, u1 = (e1b + c1e * py0) * ia;
                ins0 = fminf(u0, fminf(u1, (1.0f - u0) - u1)) >= 0.0f;
            }
            {
                float u0 = (e0b + c0e * py1) * ia, u1 = (e1b + c1e * py1) * ia;
                ins1 = fminf(u0, fminf(u1, (1.0f - u0) - u1)) >= 0.0f;
            }
            {
                float u0 = (e0b + c0e * py2) * ia, u1 = (e1b + c1e * py2) * ia;
                ins2 = fminf(u0, fminf(u1, (1.0f - u0) - u1)) >= 0.0f;
            }
            {
                float u0 = (e0b + c0e * py3) * ia, u1 = (e1b + c1e * py3) * ia;
                ins3 = fminf(u0, fminf(u1, (1.0f - u0) - u1)) >= 0.0f;
            }
        }
        best0 = ins0 ? fmaxf(best0, zi0) : best0;
        best1 = ins1 ? fmaxf(best1, zi1) : best1;
        best2 = ins2 ? fmaxf(best2, zi2) : best2;
        best3 = ins3 ? fmaxf(best3, zi3) : best3;
    }

    const size_t base = (size_t)b * (SS * SS) + (size_t)irow0 * SS + j;
    if (best0 > 0.0f) atomicMin(&zu[base + 0 * 4 * SS], __float_as_uint(1.0f / best0));
    if (best1 > 0.0f) atomicMin(&zu[base + 1 * 4 * SS], __float_as_uint(1.0f / best1));
    if (best2 > 0.0f) atomicMin(&zu[base + 2 * 4 * SS], __float_as_uint(1.0f / best2));
    if (best3 > 0.0f) atomicMin(&zu[base + 3 * 4 * SS], __float_as_uint(1.0f / best3));
}

// ---------------- final: uint zbuf -> (sil, z) ----------------
__global__ void nmr_final(float* __restrict__ out, int B)
{
    int idx = blockIdx.x * 256 + threadIdx.x;
    if (idx >= B * SS * SS) return;
    uint32_t* zu = (uint32_t*)(out + (size_t)B * SS * SS);
    uint32_t u = zu[idx];
    bool cov = (u != 0xFFFFFFFFu);
    out[idx] = cov ? 1.0f : 0.0f;
    ((float*)zu)[idx] = cov ? __uint_as_float(u) : FAR_F;
}

// ---------------- host ----------------
extern "C" void kernel_launch(void* const* d_in, const int* in_sizes, int n_in,
                              void* d_out, int out_size, void* d_ws, size_t ws_size,
                              hipStream_t stream)
{
    const float* verts = (const float*)d_in[0];
    const int*   faces = (const int*)d_in[1];
    float* out = (float*)d_out;

    const int B = out_size / (2 * SS * SS);          // 16
    const int F = in_sizes[1] / 3;                   // 1538
    const int N = in_sizes[0] / (3 * B);             // 778

    PackedCoef* pc = (PackedCoef*)d_ws;
    uint32_t*  bbx = (uint32_t*)((char*)d_ws + (size_t)B * F * sizeof(PackedCoef));
    uint32_t*  zu  = (uint32_t*)(out + (size_t)B * SS * SS);  // zbuf-as-uint lives in zb output region

    // reset z-buffer to 0xFFFFFFFF (max uint; any valid z-bits are smaller)
    hipMemsetAsync(zu, 0xFF, (size_t)B * SS * SS * sizeof(uint32_t), stream);

    const int total = B * F;
    nmr_prep<<<(total + 255) / 256, 256, 0, stream>>>(verts, faces, pc, bbx, B, N, F);

    const int NCHn = (F + CAPB - 1) / CAPB;          // 6 for F=1538
    const int CH = (F + NCHn - 1) / NCHn;            // 257 <= CAPB
    nmr_raster<<<B * NREG * NCHn, 256, 0, stream>>>(pc, bbx, verts, faces, zu, B, N, F, NCHn, CH);

    nmr_final<<<(B * SS * SS + 255) / 256, 256, 0, stream>>>(out, B);
}

// Round 4
// 107.802 us; speedup vs baseline: 4.6133x; 2.0124x over previous
//
#include <hip/hip_runtime.h>
#include <stdint.h>

#define SS 256
#define FAR_F 100.0f
#define REG 32             // region size in px
#define NREG 64            // regions per batch (8x8)
#define NCH 6              // face chunks
#define CHMAX 260          // >= ceil(F/NCH) = 257 for F=1538

struct __align__(16) PackedCoef {
    float4 q0;  // A0,B0,C0,A1   (edge coefs premultiplied by inv_area)
    float4 q1;  // B1,C1,Zx,Zy   (zinv = Z0 + Zx*px + Zy*py)
    float4 q2;  // Z0, e_face, bits(bbox), bits(faceid)
};

// ---------------- prep: per (b,f) packed coefficients + bbox ----------------
__global__ void nmr_prep(const float* __restrict__ verts,
                         const int* __restrict__ faces,
                         PackedCoef* __restrict__ pc,
                         uint32_t* __restrict__ bbx,
                         int B, int N, int F)
{
#pragma clang fp contract(off)
    int idx = blockIdx.x * blockDim.x + threadIdx.x;
    if (idx >= B * F) return;
    int b = idx / F;
    int f = idx - b * F;

    int i0 = faces[3 * f + 0], i1 = faces[3 * f + 1], i2 = faces[3 * f + 2];
    const float* vb = verts + (size_t)(3 * N) * b;
    const float EZ = -1.7320508075688772f;  // f32(EYE_Z)

    float x0 = vb[3 * i0 + 0], y0 = -vb[3 * i0 + 1], z0 = vb[3 * i0 + 2] - EZ;
    float x1 = vb[3 * i1 + 0], y1 = -vb[3 * i1 + 1], z1 = vb[3 * i1 + 2] - EZ;
    float x2 = vb[3 * i2 + 0], y2 = -vb[3 * i2 + 1], z2 = vb[3 * i2 + 2] - EZ;

    float area = (x1 - x0) * (y2 - y0) - (x2 - x0) * (y1 - y0);
    bool ok = fabsf(area) > 1e-7f;
    float ia = ok ? (1.0f / area) : 0.0f;

    // premultiplied edge coefs
    float A0 = (x1 * y2 - x2 * y1) * ia, B0 = (y1 - y2) * ia, C0 = (x2 - x1) * ia;
    float A1 = (x2 * y0 - x0 * y2) * ia, B1 = (y2 - y0) * ia, C1 = (x0 - x2) * ia;
    float rz0 = 1.0f / z0, rz1 = 1.0f / z1, rz2 = 1.0f / z2;
    float d0 = rz0 - rz2, d1 = rz1 - rz2;
    // zinv affine form
    float Z0 = rz2 + A0 * d0 + A1 * d1;
    float Zx = B0 * d0 + B1 * d1;
    float Zy = C0 * d0 + C1 * d1;
    // rigorous per-face ambiguity half-width (valid at every pixel: |px|,|py|<1)
    float S = fabsf(A0) + fabsf(B0) + fabsf(C0) + fabsf(A1) + fabsf(B1) + fabsf(C1) + 1.0f;
    float ef = 3e-6f * S;

    // conservative pixel bbox (padded +-1 px); empty if degenerate
    uint32_t bb = 255u | (0u << 8) | (255u << 16) | (0u << 24);
    if (ok) {
        float xmn = fminf(x0, fminf(x1, x2)), xmx = fmaxf(x0, fmaxf(x1, x2));
        float ymn = fminf(y0, fminf(y1, y2)), ymx = fmaxf(y0, fmaxf(y1, y2));
        int jlo = (int)floorf(128.0f * (xmn + 1.0f) - 0.5f) - 1;
        int jhi = (int)ceilf (128.0f * (xmx + 1.0f) - 0.5f) + 1;
        int ilo = (int)floorf((255.0f - 256.0f * ymx) * 0.5f) - 1;
        int ihi = (int)ceilf ((255.0f - 256.0f * ymn) * 0.5f) + 1;
        jlo = max(0, min(255, jlo)); jhi = max(0, min(255, jhi));
        ilo = max(0, min(255, ilo)); ihi = max(0, min(255, ihi));
        if (jhi >= jlo && ihi >= ilo)
            bb = (uint32_t)jlo | ((uint32_t)jhi << 8) | ((uint32_t)ilo << 16) | ((uint32_t)ihi << 24);
    }

    PackedCoef c;
    c.q0 = make_float4(A0, B0, C0, A1);
    c.q1 = make_float4(B1, C1, Zx, Zy);
    c.q2 = make_float4(Z0, ef, __uint_as_float(bb), __uint_as_float((uint32_t)f));
    pc[idx] = c;
    bbx[idx] = bb;
}

// ---------------- raster: block = (batch, 32x32 region, face-chunk) ----------------
__global__ __launch_bounds__(256, 6) void nmr_raster(
    const PackedCoef* __restrict__ pc,
    const uint32_t* __restrict__ bbx,
    const float* __restrict__ verts,
    const int* __restrict__ faces,
    uint32_t* __restrict__ zu,
    int B, int N, int F, int CH)
{
#pragma clang fp contract(off)
    __shared__ float4 buf[3 * CHMAX];   // partial recs from front (3 slots), full recs from back (1 slot)
    __shared__ int cnt_p, cnt_f;

    const int bid = blockIdx.x;
    const int ch = bid % NCH; int t = bid / NCH;
    const int reg = t % NREG; const int b = t / NREG;
    const int rj0 = (reg & 7) * REG;
    const int ri0 = (reg >> 3) * REG;

    if (threadIdx.x == 0) { cnt_p = 0; cnt_f = 0; }
    __syncthreads();

    // phase 1: bbox cull -> corner classify (reject / full / partial) -> stage
    const int f0 = ch * CH, f1 = min(F, f0 + CH);
    const uint32_t* bb = bbx + (size_t)b * F;
    const PackedCoef* pb = pc + (size_t)b * F;

    const float cxa = (float)(2 * rj0 + 1 - SS) * (1.0f / SS);
    const float cxb = (float)(2 * (rj0 + REG - 1) + 1 - SS) * (1.0f / SS);
    const float cya = (float)(SS - 1 - 2 * ri0) * (1.0f / SS);
    const float cyb = (float)(SS - 1 - 2 * (ri0 + REG - 1)) * (1.0f / SS);

    for (int f = f0 + (int)threadIdx.x; f < f1; f += 256) {
        uint32_t v = bb[f];
        int jlo = v & 255, jhi = (v >> 8) & 255, ilo = (v >> 16) & 255, ihi = (int)(v >> 24);
        if (jlo > rj0 + REG - 1 || jhi < rj0 || ilo > ri0 + REG - 1 || ihi < ri0) continue;
        PackedCoef P = pb[f];
        // edge 0 at 4 corners
        float b0a = __builtin_fmaf(P.q0.y, cxa, P.q0.x), b0b = __builtin_fmaf(P.q0.y, cxb, P.q0.x);
        float w0aa = __builtin_fmaf(P.q0.z, cya, b0a), w0ab = __builtin_fmaf(P.q0.z, cyb, b0a);
        float w0ba = __builtin_fmaf(P.q0.z, cya, b0b), w0bb = __builtin_fmaf(P.q0.z, cyb, b0b);
        // edge 1
        float b1a = __builtin_fmaf(P.q1.x, cxa, P.q0.w), b1b = __builtin_fmaf(P.q1.x, cxb, P.q0.w);
        float w1aa = __builtin_fmaf(P.q1.y, cya, b1a), w1ab = __builtin_fmaf(P.q1.y, cyb, b1a);
        float w1ba = __builtin_fmaf(P.q1.y, cya, b1b), w1bb = __builtin_fmaf(P.q1.y, cyb, b1b);
        // edge 2 = (1 - w0) - w1 at matched corners
        float w2aa = (1.0f - w0aa) - w1aa, w2ab = (1.0f - w0ab) - w1ab;
        float w2ba = (1.0f - w0ba) - w1ba, w2bb = (1.0f - w0bb) - w1bb;

        float m0n = fminf(fminf(w0aa, w0ab), fminf(w0ba, w0bb));
        float m0x = fmaxf(fmaxf(w0aa, w0ab), fmaxf(w0ba, w0bb));
        float m1n = fminf(fminf(w1aa, w1ab), fminf(w1ba, w1bb));
        float m1x = fmaxf(fmaxf(w1aa, w1ab), fmaxf(w1ba, w1bb));
        float m2n = fminf(fminf(w2aa, w2ab), fminf(w2ba, w2bb));
        float m2x = fmaxf(fmaxf(w2aa, w2ab), fmaxf(w2ba, w2bb));

        float Rm = 2.0f * P.q2.y;
        if (m0x < -Rm || m1x < -Rm || m2x < -Rm) continue;          // region fully outside an edge
        if (m0n > Rm && m1n > Rm && m2n > Rm) {                     // region fully inside
            int q = atomicAdd(&cnt_f, 1);
            buf[3 * CHMAX - 1 - q] = make_float4(P.q2.x, P.q1.z, P.q1.w, 0.0f); // Z0,Zx,Zy
        } else {
            int p = atomicAdd(&cnt_p, 1);
            buf[3 * p + 0] = P.q0; buf[3 * p + 1] = P.q1; buf[3 * p + 2] = P.q2;
        }
    }
    __syncthreads();

    const int np = cnt_p, nf = cnt_f;
    const int lane = threadIdx.x & 63, w = threadIdx.x >> 6;
    const int wj0 = rj0 + ((w & 1) << 4);
    const int wi0 = ri0 + ((w >> 1) << 4);
    const int j = wj0 + (lane & 15);
    const int i0r = wi0 + (lane >> 4);                 // rows i0r + 4r
    const float px = (float)(2 * j + 1 - SS) * (1.0f / SS);
    const float py0 = (float)(SS - 1 - 2 * (i0r + 0))  * (1.0f / SS);
    const float py1 = (float)(SS - 1 - 2 * (i0r + 4))  * (1.0f / SS);
    const float py2 = (float)(SS - 1 - 2 * (i0r + 8))  * (1.0f / SS);
    const float py3 = (float)(SS - 1 - 2 * (i0r + 12)) * (1.0f / SS);

    float best0 = 0.0f, best1 = 0.0f, best2 = 0.0f, best3 = 0.0f;

    // full-accept faces: zinv eval + max only
    for (int k = 0; k < nf; ++k) {
        float4 z = buf[3 * CHMAX - 1 - k];
        float zb = __builtin_fmaf(z.y, px, z.x);
        best0 = fmaxf(best0, __builtin_fmaf(z.z, py0, zb));
        best1 = fmaxf(best1, __builtin_fmaf(z.z, py1, zb));
        best2 = fmaxf(best2, __builtin_fmaf(z.z, py2, zb));
        best3 = fmaxf(best3, __builtin_fmaf(z.z, py3, zb));
    }

    // partial faces: full inside test with ambiguity fallback
    for (int k = 0; k < np; ++k) {
        float4 q0 = buf[3 * k + 0];
        float4 q1 = buf[3 * k + 1];
        float4 q2 = buf[3 * k + 2];
        uint32_t bv = __float_as_uint(q2.z);
        int jlo = bv & 255, jhi = (bv >> 8) & 255, ilo = (bv >> 16) & 255, ihi = (int)(bv >> 24);
        if (jlo > wj0 + 15 || jhi < wj0 || ilo > wi0 + 15 || ihi < wi0) continue;

        const float ef = q2.y;
        float w0b = __builtin_fmaf(q0.y, px, q0.x);
        float w1b = __builtin_fmaf(q1.x, px, q0.w);
        float zbv = __builtin_fmaf(q1.z, px, q2.x);

        float w0_0 = __builtin_fmaf(q0.z, py0, w0b), w1_0 = __builtin_fmaf(q1.y, py0, w1b);
        float w0_1 = __builtin_fmaf(q0.z, py1, w0b), w1_1 = __builtin_fmaf(q1.y, py1, w1b);
        float w0_2 = __builtin_fmaf(q0.z, py2, w0b), w1_2 = __builtin_fmaf(q1.y, py2, w1b);
        float w0_3 = __builtin_fmaf(q0.z, py3, w0b), w1_3 = __builtin_fmaf(q1.y, py3, w1b);
        float m0 = fminf(w0_0, fminf(w1_0, (1.0f - w0_0) - w1_0));
        float m1 = fminf(w0_1, fminf(w1_1, (1.0f - w0_1) - w1_1));
        float m2 = fminf(w0_2, fminf(w1_2, (1.0f - w0_2) - w1_2));
        float m3 = fminf(w0_3, fminf(w1_3, (1.0f - w0_3) - w1_3));
        float zi0 = __builtin_fmaf(q1.w, py0, zbv);
        float zi1 = __builtin_fmaf(q1.w, py1, zbv);
        float zi2 = __builtin_fmaf(q1.w, py2, zbv);
        float zi3 = __builtin_fmaf(q1.w, py3, zbv);
        bool ins0 = m0 >= 0.0f, ins1 = m1 >= 0.0f, ins2 = m2 >= 0.0f, ins3 = m3 >= 0.0f;
        bool amb = (fabsf(m0) <= ef) | (fabsf(m1) <= ef) | (fabsf(m2) <= ef) | (fabsf(m3) <= ef);

        if (__any(amb)) {
            // exact numpy-order recompute (rare); staged faces are non-degenerate
            int fid = __builtin_amdgcn_readfirstlane((int)__float_as_uint(q2.w));
            int i0f = faces[3 * fid + 0], i1f = faces[3 * fid + 1], i2f = faces[3 * fid + 2];
            const float* vb = verts + (size_t)(3 * N) * b;
            float x0 = vb[3 * i0f + 0], y0 = -vb[3 * i0f + 1];
            float x1 = vb[3 * i1f + 0], y1 = -vb[3 * i1f + 1];
            float x2 = vb[3 * i2f + 0], y2 = -vb[3 * i2f + 1];
            float area = (x1 - x0) * (y2 - y0) - (x2 - x0) * (y1 - y0);
            float ia = 1.0f / area;
            float a0 = x1 * y2 - x2 * y1, b0e = y1 - y2, c0e = x2 - x1;
            float a1 = x2 * y0 - x0 * y2, b1e = y2 - y0, c1e = x0 - x2;
            float e0b = a0 + b0e * px;
            float e1b = a1 + b1e * px;
            { float u0 = (e0b + c0e * py0) * ia, u1 = (e1b + c1e * py0) * ia;
              ins0 = fminf(u0, fminf(u1, (1.0f - u0) - u1)) >= 0.0f; }
            { float u0 = (e0b + c0e * py1) * ia, u1 = (e1b + c1e * py1) * ia;
              ins1 = fminf(u0, fminf(u1, (1.0f - u0) - u1)) >= 0.0f; }
            { float u0 = (e0b + c0e * py2) * ia, u1 = (e1b + c1e * py2) * ia;
              ins2 = fminf(u0, fminf(u1, (1.0f - u0) - u1)) >= 0.0f; }
            { float u0 = (e0b + c0e * py3) * ia, u1 = (e1b + c1e * py3) * ia;
              ins3 = fminf(u0, fminf(u1, (1.0f - u0) - u1)) >= 0.0f; }
        }
        best0 = ins0 ? fmaxf(best0, zi0) : best0;
        best1 = ins1 ? fmaxf(best1, zi1) : best1;
        best2 = ins2 ? fmaxf(best2, zi2) : best2;
        best3 = ins3 ? fmaxf(best3, zi3) : best3;
    }

    const size_t base = (size_t)b * (SS * SS) + (size_t)i0r * SS + j;
    if (best0 > 0.0f) atomicMin(&zu[base + 0 * 4 * SS], __float_as_uint(1.0f / best0));
    if (best1 > 0.0f) atomicMin(&zu[base + 1 * 4 * SS], __float_as_uint(1.0f / best1));
    if (best2 > 0.0f) atomicMin(&zu[base + 2 * 4 * SS], __float_as_uint(1.0f / best2));
    if (best3 > 0.0f) atomicMin(&zu[base + 3 * 4 * SS], __float_as_uint(1.0f / best3));
}

// ---------------- final: uint zbuf -> (sil, z) ----------------
__global__ void nmr_final(float* __restrict__ out, int B)
{
    int idx = blockIdx.x * 256 + threadIdx.x;
    if (idx >= B * SS * SS) return;
    uint32_t* zu = (uint32_t*)(out + (size_t)B * SS * SS);
    uint32_t u = zu[idx];
    bool cov = (u != 0xFFFFFFFFu);
    out[idx] = cov ? 1.0f : 0.0f;
    ((float*)zu)[idx] = cov ? __uint_as_float(u) : FAR_F;
}

// ---------------- host ----------------
extern "C" void kernel_launch(void* const* d_in, const int* in_sizes, int n_in,
                              void* d_out, int out_size, void* d_ws, size_t ws_size,
                              hipStream_t stream)
{
    const float* verts = (const float*)d_in[0];
    const int*   faces = (const int*)d_in[1];
    float* out = (float*)d_out;

    const int B = out_size / (2 * SS * SS);          // 16
    const int F = in_sizes[1] / 3;                   // 1538
    const int N = in_sizes[0] / (3 * B);             // 778

    PackedCoef* pc = (PackedCoef*)d_ws;
    uint32_t*  bbx = (uint32_t*)((char*)d_ws + (size_t)B * F * sizeof(PackedCoef));
    uint32_t*  zu  = (uint32_t*)(out + (size_t)B * SS * SS);

    hipMemsetAsync(zu, 0xFF, (size_t)B * SS * SS * sizeof(uint32_t), stream);

    const int total = B * F;
    nmr_prep<<<(total + 255) / 256, 256, 0, stream>>>(verts, faces, pc, bbx, B, N, F);

    const int CH = (F + NCH - 1) / NCH;              // 257 <= CHMAX
    nmr_raster<<<B * NREG * NCH, 256, 0, stream>>>(pc, bbx, verts, faces, zu, B, N, F, CH);

    nmr_final<<<(B * SS * SS + 255) / 256, 256, 0, stream>>>(out, B);
}

// Round 5
// 95.887 us; speedup vs baseline: 5.1865x; 1.1243x over previous
//
#include <hip/hip_runtime.h>
#include <stdint.h>

#define SS 256
#define FAR_F 100.0f
#define REG 32             // region size in px
#define NREG 64            // regions per batch (8x8)
#define NCH 3              // face chunks
#define CHMAX 520          // >= ceil(F/NCH) = 513 for F=1538

struct __align__(16) PackedCoef {
    float4 q0;  // A0,B0,C0,A1   (edge coefs premultiplied by inv_area)
    float4 q1;  // B1,C1,Zx,Zy   (zinv = Z0 + Zx*px + Zy*py)
    float4 q2;  // Z0, e_face, bits(bbox), bits(faceid)
};

// ---------------- prep: per (b,f) packed coefficients + bbox ----------------
__global__ void nmr_prep(const float* __restrict__ verts,
                         const int* __restrict__ faces,
                         PackedCoef* __restrict__ pc,
                         uint32_t* __restrict__ bbx,
                         int B, int N, int F)
{
#pragma clang fp contract(off)
    int idx = blockIdx.x * blockDim.x + threadIdx.x;
    if (idx >= B * F) return;
    int b = idx / F;
    int f = idx - b * F;

    int i0 = faces[3 * f + 0], i1 = faces[3 * f + 1], i2 = faces[3 * f + 2];
    const float* vb = verts + (size_t)(3 * N) * b;
    const float EZ = -1.7320508075688772f;  // f32(EYE_Z)

    float x0 = vb[3 * i0 + 0], y0 = -vb[3 * i0 + 1], z0 = vb[3 * i0 + 2] - EZ;
    float x1 = vb[3 * i1 + 0], y1 = -vb[3 * i1 + 1], z1 = vb[3 * i1 + 2] - EZ;
    float x2 = vb[3 * i2 + 0], y2 = -vb[3 * i2 + 1], z2 = vb[3 * i2 + 2] - EZ;

    float area = (x1 - x0) * (y2 - y0) - (x2 - x0) * (y1 - y0);
    bool ok = fabsf(area) > 1e-7f;
    float ia = ok ? (1.0f / area) : 0.0f;

    // premultiplied edge coefs
    float A0 = (x1 * y2 - x2 * y1) * ia, B0 = (y1 - y2) * ia, C0 = (x2 - x1) * ia;
    float A1 = (x2 * y0 - x0 * y2) * ia, B1 = (y2 - y0) * ia, C1 = (x0 - x2) * ia;
    float rz0 = 1.0f / z0, rz1 = 1.0f / z1, rz2 = 1.0f / z2;
    float d0 = rz0 - rz2, d1 = rz1 - rz2;
    // zinv affine form
    float Z0 = rz2 + A0 * d0 + A1 * d1;
    float Zx = B0 * d0 + B1 * d1;
    float Zy = C0 * d0 + C1 * d1;
    // rigorous per-face ambiguity half-width (valid at every pixel: |px|,|py|<1)
    float S = fabsf(A0) + fabsf(B0) + fabsf(C0) + fabsf(A1) + fabsf(B1) + fabsf(C1) + 1.0f;
    float ef = 3e-6f * S;

    // conservative pixel bbox (padded +-1 px); empty if degenerate
    uint32_t bb = 255u | (0u << 8) | (255u << 16) | (0u << 24);
    if (ok) {
        float xmn = fminf(x0, fminf(x1, x2)), xmx = fmaxf(x0, fmaxf(x1, x2));
        float ymn = fminf(y0, fminf(y1, y2)), ymx = fmaxf(y0, fmaxf(y1, y2));
        int jlo = (int)floorf(128.0f * (xmn + 1.0f) - 0.5f) - 1;
        int jhi = (int)ceilf (128.0f * (xmx + 1.0f) - 0.5f) + 1;
        int ilo = (int)floorf((255.0f - 256.0f * ymx) * 0.5f) - 1;
        int ihi = (int)ceilf ((255.0f - 256.0f * ymn) * 0.5f) + 1;
        jlo = max(0, min(255, jlo)); jhi = max(0, min(255, jhi));
        ilo = max(0, min(255, ilo)); ihi = max(0, min(255, ihi));
        if (jhi >= jlo && ihi >= ilo)
            bb = (uint32_t)jlo | ((uint32_t)jhi << 8) | ((uint32_t)ilo << 16) | ((uint32_t)ihi << 24);
    }

    PackedCoef c;
    c.q0 = make_float4(A0, B0, C0, A1);
    c.q1 = make_float4(B1, C1, Zx, Zy);
    c.q2 = make_float4(Z0, ef, __uint_as_float(bb), __uint_as_float((uint32_t)f));
    pc[idx] = c;
    bbx[idx] = bb;
}

// ---------------- raster: block = (batch, 32x32 region, face-chunk) ----------------
__global__ __launch_bounds__(256, 5) void nmr_raster(
    const PackedCoef* __restrict__ pc,
    const uint32_t* __restrict__ bbx,
    const float* __restrict__ verts,
    const int* __restrict__ faces,
    uint32_t* __restrict__ zu,
    int B, int N, int F, int CH)
{
#pragma clang fp contract(off)
    __shared__ float4 pool[3 * CHMAX];   // partial recs from front (3 slots), full recs from back (1 slot)
    __shared__ float  skey[CHMAX];       // partial: zinv upper bound over region
    __shared__ uint32_t sbb[CHMAX];      // partial: face bbox
    __shared__ int cnt_p, cnt_f;

    const int bid = blockIdx.x;
    const int ch = bid % NCH; int t = bid / NCH;
    const int reg = t % NREG; const int b = t / NREG;
    const int rj0 = (reg & 7) * REG;
    const int ri0 = (reg >> 3) * REG;

    if (threadIdx.x == 0) { cnt_p = 0; cnt_f = 0; }
    __syncthreads();

    // phase 1: bbox cull -> corner classify (reject / full / partial) -> stage + z key
    const int f0 = ch * CH, f1 = min(F, f0 + CH);
    const uint32_t* bb = bbx + (size_t)b * F;
    const PackedCoef* pb = pc + (size_t)b * F;

    const float cxa = (float)(2 * rj0 + 1 - SS) * (1.0f / SS);
    const float cxb = (float)(2 * (rj0 + REG - 1) + 1 - SS) * (1.0f / SS);
    const float cya = (float)(SS - 1 - 2 * ri0) * (1.0f / SS);
    const float cyb = (float)(SS - 1 - 2 * (ri0 + REG - 1)) * (1.0f / SS);

    for (int f = f0 + (int)threadIdx.x; f < f1; f += 256) {
        uint32_t v = bb[f];
        int jlo = v & 255, jhi = (v >> 8) & 255, ilo = (v >> 16) & 255, ihi = (int)(v >> 24);
        if (jlo > rj0 + REG - 1 || jhi < rj0 || ilo > ri0 + REG - 1 || ihi < ri0) continue;
        PackedCoef P = pb[f];
        // edge 0 at 4 corners
        float b0a = __builtin_fmaf(P.q0.y, cxa, P.q0.x), b0b = __builtin_fmaf(P.q0.y, cxb, P.q0.x);
        float w0aa = __builtin_fmaf(P.q0.z, cya, b0a), w0ab = __builtin_fmaf(P.q0.z, cyb, b0a);
        float w0ba = __builtin_fmaf(P.q0.z, cya, b0b), w0bb = __builtin_fmaf(P.q0.z, cyb, b0b);
        // edge 1
        float b1a = __builtin_fmaf(P.q1.x, cxa, P.q0.w), b1b = __builtin_fmaf(P.q1.x, cxb, P.q0.w);
        float w1aa = __builtin_fmaf(P.q1.y, cya, b1a), w1ab = __builtin_fmaf(P.q1.y, cyb, b1a);
        float w1ba = __builtin_fmaf(P.q1.y, cya, b1b), w1bb = __builtin_fmaf(P.q1.y, cyb, b1b);
        // edge 2 = (1 - w0) - w1 at matched corners
        float w2aa = (1.0f - w0aa) - w1aa, w2ab = (1.0f - w0ab) - w1ab;
        float w2ba = (1.0f - w0ba) - w1ba, w2bb = (1.0f - w0bb) - w1bb;

        float m0n = fminf(fminf(w0aa, w0ab), fminf(w0ba, w0bb));
        float m0x = fmaxf(fmaxf(w0aa, w0ab), fmaxf(w0ba, w0bb));
        float m1n = fminf(fminf(w1aa, w1ab), fminf(w1ba, w1bb));
        float m1x = fmaxf(fmaxf(w1aa, w1ab), fmaxf(w1ba, w1bb));
        float m2n = fminf(fminf(w2aa, w2ab), fminf(w2ba, w2bb));
        float m2x = fmaxf(fmaxf(w2aa, w2ab), fmaxf(w2ba, w2bb));

        float Rm = 2.0f * P.q2.y;
        if (m0x < -Rm || m1x < -Rm || m2x < -Rm) continue;          // region fully outside an edge

        // zinv upper bound over region (affine -> max at corners) + conservative margin
        float za = __builtin_fmaf(P.q1.z, cxa, P.q2.x), zbq = __builtin_fmaf(P.q1.z, cxb, P.q2.x);
        float z_aa = __builtin_fmaf(P.q1.w, cya, za),  z_ab = __builtin_fmaf(P.q1.w, cyb, za);
        float z_ba = __builtin_fmaf(P.q1.w, cya, zbq), z_bb = __builtin_fmaf(P.q1.w, cyb, zbq);
        float cmax = fmaxf(fmaxf(z_aa, z_ab), fmaxf(z_ba, z_bb));
        float key = cmax + __builtin_fmaf(fabsf(cmax), 1e-6f, 1e-5f);

        if (m0n > Rm && m1n > Rm && m2n > Rm) {                     // region fully inside
            int q = atomicAdd(&cnt_f, 1);
            pool[3 * CHMAX - 1 - q] = make_float4(P.q2.x, P.q1.z, P.q1.w, key); // Z0,Zx,Zy,key
        } else {
            int p = atomicAdd(&cnt_p, 1);
            pool[3 * p + 0] = P.q0; pool[3 * p + 1] = P.q1; pool[3 * p + 2] = P.q2;
            skey[p] = key;
            sbb[p] = __float_as_uint(P.q2.z);
        }
    }
    __syncthreads();

    const int np = cnt_p, nf = cnt_f;
    const int lane = threadIdx.x & 63, w = threadIdx.x >> 6;
    const int wj0 = rj0 + ((w & 1) << 4);
    const int wi0 = ri0 + ((w >> 1) << 4);
    const int j = wj0 + (lane & 15);
    const int i0r = wi0 + (lane >> 4);                 // rows i0r + 4r
    const float px = (float)(2 * j + 1 - SS) * (1.0f / SS);
    const float py0 = (float)(SS - 1 - 2 * (i0r + 0))  * (1.0f / SS);
    const float py1 = (float)(SS - 1 - 2 * (i0r + 4))  * (1.0f / SS);
    const float py2 = (float)(SS - 1 - 2 * (i0r + 8))  * (1.0f / SS);
    const float py3 = (float)(SS - 1 - 2 * (i0r + 12)) * (1.0f / SS);

    float best0 = 0.0f, best1 = 0.0f, best2 = 0.0f, best3 = 0.0f;

    // full-accept faces first (raises best cheaply -> better occlusion skips later)
    for (int k = 0; k < nf; ++k) {
        float4 z = pool[3 * CHMAX - 1 - k];
        float lanemin = fminf(fminf(best0, best1), fminf(best2, best3));
        if (__all(z.w <= lanemin)) continue;           // can't improve any pixel in wave
        float zb = __builtin_fmaf(z.y, px, z.x);
        best0 = fmaxf(best0, __builtin_fmaf(z.z, py0, zb));
        best1 = fmaxf(best1, __builtin_fmaf(z.z, py1, zb));
        best2 = fmaxf(best2, __builtin_fmaf(z.z, py2, zb));
        best3 = fmaxf(best3, __builtin_fmaf(z.z, py3, zb));
    }

    // partial faces: occlusion skip -> wave bbox skip -> full inside test (+amb fallback)
    for (int k = 0; k < np; ++k) {
        float key = skey[k];
        float lanemin = fminf(fminf(best0, best1), fminf(best2, best3));
        if (__all(key <= lanemin)) continue;           // occluded for every px in wave: exact no-op
        uint32_t bv = sbb[k];
        int jlo = bv & 255, jhi = (bv >> 8) & 255, ilo = (bv >> 16) & 255, ihi = (int)(bv >> 24);
        if (jlo > wj0 + 15 || jhi < wj0 || ilo > wi0 + 15 || ihi < wi0) continue;

        float4 q0 = pool[3 * k + 0];
        float4 q1 = pool[3 * k + 1];
        float4 q2 = pool[3 * k + 2];
        const float ef = q2.y;
        float w0b = __builtin_fmaf(q0.y, px, q0.x);
        float w1b = __builtin_fmaf(q1.x, px, q0.w);
        float zbv = __builtin_fmaf(q1.z, px, q2.x);

        float w0_0 = __builtin_fmaf(q0.z, py0, w0b), w1_0 = __builtin_fmaf(q1.y, py0, w1b);
        float w0_1 = __builtin_fmaf(q0.z, py1, w0b), w1_1 = __builtin_fmaf(q1.y, py1, w1b);
        float w0_2 = __builtin_fmaf(q0.z, py2, w0b), w1_2 = __builtin_fmaf(q1.y, py2, w1b);
        float w0_3 = __builtin_fmaf(q0.z, py3, w0b), w1_3 = __builtin_fmaf(q1.y, py3, w1b);
        float m0 = fminf(w0_0, fminf(w1_0, (1.0f - w0_0) - w1_0));
        float m1 = fminf(w0_1, fminf(w1_1, (1.0f - w0_1) - w1_1));
        float m2 = fminf(w0_2, fminf(w1_2, (1.0f - w0_2) - w1_2));
        float m3 = fminf(w0_3, fminf(w1_3, (1.0f - w0_3) - w1_3));
        float zi0 = __builtin_fmaf(q1.w, py0, zbv);
        float zi1 = __builtin_fmaf(q1.w, py1, zbv);
        float zi2 = __builtin_fmaf(q1.w, py2, zbv);
        float zi3 = __builtin_fmaf(q1.w, py3, zbv);
        bool ins0 = m0 >= 0.0f, ins1 = m1 >= 0.0f, ins2 = m2 >= 0.0f, ins3 = m3 >= 0.0f;
        bool amb = (fabsf(m0) <= ef) | (fabsf(m1) <= ef) | (fabsf(m2) <= ef) | (fabsf(m3) <= ef);

        if (__any(amb)) {
            // exact numpy-order recompute (rare); staged faces are non-degenerate
            int fid = __builtin_amdgcn_readfirstlane((int)__float_as_uint(q2.w));
            int i0f = faces[3 * fid + 0], i1f = faces[3 * fid + 1], i2f = faces[3 * fid + 2];
            const float* vb = verts + (size_t)(3 * N) * b;
            float x0 = vb[3 * i0f + 0], y0 = -vb[3 * i0f + 1];
            float x1 = vb[3 * i1f + 0], y1 = -vb[3 * i1f + 1];
            float x2 = vb[3 * i2f + 0], y2 = -vb[3 * i2f + 1];
            float area = (x1 - x0) * (y2 - y0) - (x2 - x0) * (y1 - y0);
            float ia = 1.0f / area;
            float a0 = x1 * y2 - x2 * y1, b0e = y1 - y2, c0e = x2 - x1;
            float a1 = x2 * y0 - x0 * y2, b1e = y2 - y0, c1e = x0 - x2;
            float e0b = a0 + b0e * px;
            float e1b = a1 + b1e * px;
            { float u0 = (e0b + c0e * py0) * ia, u1 = (e1b + c1e * py0) * ia;
              ins0 = fminf(u0, fminf(u1, (1.0f - u0) - u1)) >= 0.0f; }
            { float u0 = (e0b + c0e * py1) * ia, u1 = (e1b + c1e * py1) * ia;
              ins1 = fminf(u0, fminf(u1, (1.0f - u0) - u1)) >= 0.0f; }
            { float u0 = (e0b + c0e * py2) * ia, u1 = (e1b + c1e * py2) * ia;
              ins2 = fminf(u0, fminf(u1, (1.0f - u0) - u1)) >= 0.0f; }
            { float u0 = (e0b + c0e * py3) * ia, u1 = (e1b + c1e * py3) * ia;
              ins3 = fminf(u0, fminf(u1, (1.0f - u0) - u1)) >= 0.0f; }
        }
        best0 = ins0 ? fmaxf(best0, zi0) : best0;
        best1 = ins1 ? fmaxf(best1, zi1) : best1;
        best2 = ins2 ? fmaxf(best2, zi2) : best2;
        best3 = ins3 ? fmaxf(best3, zi3) : best3;
    }

    const size_t base = (size_t)b * (SS * SS) + (size_t)i0r * SS + j;
    if (best0 > 0.0f) atomicMin(&zu[base + 0 * 4 * SS], __float_as_uint(1.0f / best0));
    if (best1 > 0.0f) atomicMin(&zu[base + 1 * 4 * SS], __float_as_uint(1.0f / best1));
    if (best2 > 0.0f) atomicMin(&zu[base + 2 * 4 * SS], __float_as_uint(1.0f / best2));
    if (best3 > 0.0f) atomicMin(&zu[base + 3 * 4 * SS], __float_as_uint(1.0f / best3));
}

// ---------------- final: uint zbuf -> (sil, z) ----------------
__global__ void nmr_final(float* __restrict__ out, int B)
{
    int idx = blockIdx.x * 256 + threadIdx.x;
    if (idx >= B * SS * SS) return;
    uint32_t* zu = (uint32_t*)(out + (size_t)B * SS * SS);
    uint32_t u = zu[idx];
    bool cov = (u != 0xFFFFFFFFu);
    out[idx] = cov ? 1.0f : 0.0f;
    ((float*)zu)[idx] = cov ? __uint_as_float(u) : FAR_F;
}

// ---------------- host ----------------
extern "C" void kernel_launch(void* const* d_in, const int* in_sizes, int n_in,
                              void* d_out, int out_size, void* d_ws, size_t ws_size,
                              hipStream_t stream)
{
    const float* verts = (const float*)d_in[0];
    const int*   faces = (const int*)d_in[1];
    float* out = (float*)d_out;

    const int B = out_size / (2 * SS * SS);          // 16
    const int F = in_sizes[1] / 3;                   // 1538
    const int N = in_sizes[0] / (3 * B);             // 778

    PackedCoef* pc = (PackedCoef*)d_ws;
    uint32_t*  bbx = (uint32_t*)((char*)d_ws + (size_t)B * F * sizeof(PackedCoef));
    uint32_t*  zu  = (uint32_t*)(out + (size_t)B * SS * SS);

    hipMemsetAsync(zu, 0xFF, (size_t)B * SS * SS * sizeof(uint32_t), stream);

    const int total = B * F;
    nmr_prep<<<(total + 255) / 256, 256, 0, stream>>>(verts, faces, pc, bbx, B, N, F);

    const int CH = (F + NCH - 1) / NCH;              // 513 <= CHMAX
    nmr_raster<<<B * NREG * NCH, 256, 0, stream>>>(pc, bbx, verts, faces, zu, B, N, F, CH);

    nmr_final<<<(B * SS * SS + 255) / 256, 256, 0, stream>>>(out, B);
}